// Round 13
// baseline (261.886 us; speedup 1.0000x reference)
//
#include <hip/hip_runtime.h>
#include <hip/hip_bf16.h>

// Problem constants
#define BB   16
#define CIN  512
#define COUT 512
#define KS   3
#define KK   9
#define HH   32
#define WW   32
#define HW   1024
#define SDIM 512
#define RR   512
#define MM   4608               // KK*CIN; m = kk*512 + ci
#define MT   144                // MM/32 k-tiles
#define SCALE_F 0.014731391274719738f  // 1/sqrt(4608)

typedef __attribute__((ext_vector_type(8))) short bf16x8;
typedef __attribute__((ext_vector_type(4))) float f32x4;

__device__ __forceinline__ void gload_lds16(const void* g, void* l) {
    __builtin_amdgcn_global_load_lds(
        (const __attribute__((address_space(1))) unsigned int*)g,
        (__attribute__((address_space(3))) unsigned int*)l,
        16, 0, 0);
}

#define PIPE_WAIT(N) do {                                            \
    asm volatile("s_waitcnt vmcnt(" #N ")" ::: "memory");            \
    __builtin_amdgcn_s_barrier();                                    \
    __builtin_amdgcn_sched_barrier(0); } while (0)
#define PIPE_END() do {                                              \
    __builtin_amdgcn_sched_barrier(0);                               \
    __builtin_amdgcn_s_barrier(); } while (0)

// ---------------------------------------------------------------------------
// K_prep: ONE kernel for every input-only transform (block-uniform sections).
//  [0,32)      : s[b,ci] = style . mw^T + mb
//  [32,608)    : ubf[m][r]=bf16(u), ubfT[r][m]=bf16(u)   (72x8 tiles)
//  [608,736)   : vhb = bf16(vh)
//  [736,1760)  : vt[b][co][r] = bf16(ev_b[r]*vh[r][co])
//  [1760,2272) : wgtb[co][kk][ci] = bf16(weight[co][ci][kk])
//  [2272,2784) : xpose interior (x -> xh NHWC bf16)
//  [2784,2800) : xh halo zero (one block per b)
//  [2800,2805) : zero demodsq+normsq (8208 floats)
//  [2805,3061) : zero Gu+Gv (524288 floats)
// ---------------------------------------------------------------------------
__global__ __launch_bounds__(256) void k_prep(
        const float* __restrict__ style, const float* __restrict__ mw,
        const float* __restrict__ mb, float* __restrict__ s,
        const float* __restrict__ u, __hip_bfloat16* __restrict__ ub,
        __hip_bfloat16* __restrict__ uT,
        const float* __restrict__ vh, __hip_bfloat16* __restrict__ vhb,
        const float* __restrict__ dd, const int* __restrict__ dirs,
        __hip_bfloat16* __restrict__ vt,
        const float* __restrict__ wgt, __hip_bfloat16* __restrict__ wgtb,
        const float* __restrict__ x, __hip_bfloat16* __restrict__ xh,
        float* __restrict__ zero1, float* __restrict__ zero2) {
    const int id = blockIdx.x;
    const int t = threadIdx.x;
    __shared__ __align__(16) char shbuf[18432];

    if (id < 32) {
        int idx = id * 256 + t;
        int b = idx >> 9, ci = idx & 511;
        const float* st = style + (size_t)b * SDIM;
        const float* w  = mw + (size_t)ci * SDIM;
        float acc = 0.f;
        for (int d = 0; d < SDIM; d += 4)
            acc += st[d]*w[d] + st[d+1]*w[d+1] + st[d+2]*w[d+2] + st[d+3]*w[d+3];
        s[idx] = acc + mb[ci];
    } else if (id < 608) {
        __hip_bfloat16 (*tile)[80] = (__hip_bfloat16(*)[80])shbuf;
        const int bx = id - 32;
        const int m0 = (bx % 72) * 64, r0 = (bx / 72) * 64;
        const int ml = t >> 4, rl4 = (t & 15) * 4;
        #pragma unroll
        for (int p = 0; p < 4; ++p) {
            int m_l = ml + p * 16;
            float4 v = *(const float4*)&u[(size_t)(m0 + m_l) * RR + r0 + rl4];
            __hip_bfloat16 b4[4] = {__float2bfloat16(v.x), __float2bfloat16(v.y),
                                    __float2bfloat16(v.z), __float2bfloat16(v.w)};
            *(ushort4*)&ub[(size_t)(m0 + m_l) * RR + r0 + rl4] = *(const ushort4*)b4;
            tile[rl4+0][m_l] = b4[0];
            tile[rl4+1][m_l] = b4[1];
            tile[rl4+2][m_l] = b4[2];
            tile[rl4+3][m_l] = b4[3];
        }
        __syncthreads();
        const int cl = t >> 2, rg = (t & 3) * 16;
        __hip_bfloat16* dst = uT + (size_t)(r0 + cl) * MM + m0 + rg;
        *(bf16x8*)dst       = *(const bf16x8*)&tile[cl][rg];
        *(bf16x8*)(dst + 8) = *(const bf16x8*)&tile[cl][rg + 8];
    } else if (id < 736) {
        size_t i = ((size_t)(id - 608) * 256 + t) * 8;
        float4 a = *(const float4*)(vh + i);
        float4 b = *(const float4*)(vh + i + 4);
        __hip_bfloat16 o[8] = {
            __float2bfloat16(a.x), __float2bfloat16(a.y),
            __float2bfloat16(a.z), __float2bfloat16(a.w),
            __float2bfloat16(b.x), __float2bfloat16(b.y),
            __float2bfloat16(b.z), __float2bfloat16(b.w)};
        *(bf16x8*)(vhb + i) = *(const bf16x8*)o;
    } else if (id < 1760) {
        __hip_bfloat16 (*tile)[80] = (__hip_bfloat16(*)[80])shbuf;
        const int vid = id - 736;
        const int co0 = (vid & 7) * 64, r0 = ((vid >> 3) & 7) * 64, b = vid >> 6;
        const float* ev = dd + (size_t)dirs[b] * RR;
        int tc4 = (t & 15) * 4, tr = t >> 4;
        #pragma unroll
        for (int pass = 0; pass < 4; ++pass) {
            int r = tr + pass * 16;
            float e = ev[r0 + r];
            float4 v = *(const float4*)&vh[(size_t)(r0 + r) * COUT + co0 + tc4];
            tile[tc4+0][r] = __float2bfloat16(v.x * e);
            tile[tc4+1][r] = __float2bfloat16(v.y * e);
            tile[tc4+2][r] = __float2bfloat16(v.z * e);
            tile[tc4+3][r] = __float2bfloat16(v.w * e);
        }
        __syncthreads();
        int cl = t >> 2, rg = (t & 3) * 16;
        __hip_bfloat16* dst = vt + ((size_t)b * COUT + co0 + cl) * RR + r0 + rg;
        *(bf16x8*)dst       = *(const bf16x8*)&tile[cl][rg];
        *(bf16x8*)(dst + 8) = *(const bf16x8*)&tile[cl][rg + 8];
    } else if (id < 2272) {
        float* lw = (float*)shbuf;
        const int co = id - 1760;
        for (int e = t; e < MM; e += 256) lw[e] = wgt[(size_t)co * MM + e];
        __syncthreads();
        for (int e0 = t * 8; e0 < MM; e0 += 2048) {
            int kk = e0 >> 9, ci = e0 & 511;
            __hip_bfloat16 o[8];
            #pragma unroll
            for (int q = 0; q < 8; ++q)
                o[q] = __float2bfloat16(lw[(ci + q) * KK + kk]);
            *(bf16x8*)&wgtb[(size_t)co * MM + e0] = *(const bf16x8*)o;
        }
    } else if (id < 2784) {
        __hip_bfloat16 (*tileT)[72] = (__hip_bfloat16(*)[72])shbuf;
        const int xid = id - 2272;
        const int b = xid >> 5;
        const int y = xid & 31;
        for (int c0 = 0; c0 < CIN; c0 += 64) {
            int ci_l = t >> 2, xq = (t & 3) * 8;
            const float* src = x + (((size_t)(b * CIN + c0 + ci_l)) * HH + y) * WW + xq;
            float4 v0 = *(const float4*)src;
            float4 v1 = *(const float4*)(src + 4);
            __syncthreads();
            tileT[xq+0][ci_l] = __float2bfloat16(v0.x);
            tileT[xq+1][ci_l] = __float2bfloat16(v0.y);
            tileT[xq+2][ci_l] = __float2bfloat16(v0.z);
            tileT[xq+3][ci_l] = __float2bfloat16(v0.w);
            tileT[xq+4][ci_l] = __float2bfloat16(v1.x);
            tileT[xq+5][ci_l] = __float2bfloat16(v1.y);
            tileT[xq+6][ci_l] = __float2bfloat16(v1.z);
            tileT[xq+7][ci_l] = __float2bfloat16(v1.w);
            __syncthreads();
            int x_l = t >> 3, cg = (t & 7) * 8;
            bf16x8 o = *(const bf16x8*)&tileT[x_l][cg];
            *(bf16x8*)&xh[(((size_t)b * 34 + y + 1) * 34 + (x_l + 1)) * CIN + c0 + cg] = o;
        }
    } else if (id < 2800) {
        const int b = id - 2784;
        for (int c = t; c < 132 * 64; c += 256) {
            int cell = c >> 6, part = c & 63;
            int yy, xx;
            if (cell < 34)      { yy = 0;  xx = cell; }
            else if (cell < 68) { yy = 33; xx = cell - 34; }
            else if (cell < 100){ yy = cell - 68 + 1;  xx = 0; }
            else                { yy = cell - 100 + 1; xx = 33; }
            bf16x8 z = {0,0,0,0,0,0,0,0};
            *(bf16x8*)&xh[(((size_t)b * 34 + yy) * 34 + xx) * CIN + part * 8] = z;
        }
    } else if (id < 2805) {
        int idx = (id - 2800) * 2048 + t * 8;
        if (idx < 8208) {
            float4 z = {0.f, 0.f, 0.f, 0.f};
            *(float4*)(zero1 + idx) = z;
            *(float4*)(zero1 + idx + 4) = z;
        }
    } else {
        int idx = (id - 2805) * 2048 + t * 8;
        float4 z = {0.f, 0.f, 0.f, 0.f};
        *(float4*)(zero2 + idx) = z;
        *(float4*)(zero2 + idx + 4) = z;
    }
}

// ---------------------------------------------------------------------------
// K2: merged Gram kernel, SYMMETRIC-TRIANGLE grid.
// blockIdx.x in [0,36) decodes upper-triangle tile pair (r0<=r1);
// z<9: Gu slice; z>=9: Gv slice. Off-diagonal tiles also mirror-write.
// 64x64 tile, 4 waves (2x2 of 32x32), BK=32, 4-buffer pipeline, atomic epi.
// ---------------------------------------------------------------------------
__global__ __launch_bounds__(256) void k_gram2(
        const __hip_bfloat16* __restrict__ uT,    // [RR][MM]
        const __hip_bfloat16* __restrict__ vhb,   // [RR][COUT]
        float* __restrict__ Gu, float* __restrict__ Gv) {
    // decode upper-triangle pair
    int rem = blockIdx.x, r0i = 0;
    while (rem >= 8 - r0i) { rem -= 8 - r0i; ++r0i; }
    const int r0 = r0i * 64, r1 = (r0i + rem) * 64;
    const int z  = blockIdx.y;
    const bool isGu = (z < 9);
    const __hip_bfloat16* src = isGu ? uT : vhb;
    const int ldb   = (isGu ? MM : COUT) * 2;          // row stride bytes
    const int koff  = isGu ? z * 1024 : (z - 9) * 512; // k offset bytes
    const int NT    = isGu ? 16 : 8;
    float* G = isGu ? Gu : Gv;

    __shared__ __align__(16) char gLDS[4 * 8192];      // 32 KB
    const int t = threadIdx.x;
    const int w = t >> 6, l = t & 63;
    const int row = t >> 2, ls = t & 3;
    const int sg = ls ^ ((row >> 1) & 3);

    const char* sa = (const char*)src + (size_t)(r0 + row) * ldb + koff + sg * 16;
    const char* sb = (const char*)src + (size_t)(r1 + row) * ldb + koff + sg * 16;

    f32x4 acc[2][2];
    #pragma unroll
    for (int i = 0; i < 2; ++i)
        #pragma unroll
        for (int j = 0; j < 2; ++j) acc[i][j] = (f32x4){0.f, 0.f, 0.f, 0.f};

#define GSTAGE(bn, kt) { char* Gb_ = gLDS + (bn) * 8192;                     \
    gload_lds16(sa + (kt) * 64, Gb_ + t * 16);                               \
    gload_lds16(sb + (kt) * 64, Gb_ + 4096 + t * 16); }

#define GCOMP(bn) { const char* Ab_ = gLDS + (bn) * 8192;                    \
    const char* Bb_ = Ab_ + 4096;                                            \
    bf16x8 fa[2], fb[2];                                                     \
    const int sl = (l >> 4) << 4;                                            \
    const int ar = (w >> 1) * 32 + (l & 15);                                 \
    const int br = (w & 1) * 32 + (l & 15);                                  \
    _Pragma("unroll") for (int i = 0; i < 2; ++i) {                          \
        int r = ar + i * 16;                                                 \
        fa[i] = *(const bf16x8*)(Ab_ + r * 64 + (sl ^ (((r >> 1) & 3) << 4))); \
        int q = br + i * 16;                                                 \
        fb[i] = *(const bf16x8*)(Bb_ + q * 64 + (sl ^ (((q >> 1) & 3) << 4))); } \
    __builtin_amdgcn_s_setprio(1);                                           \
    _Pragma("unroll") for (int i = 0; i < 2; ++i)                            \
        _Pragma("unroll") for (int j = 0; j < 2; ++j)                        \
            acc[i][j] = __builtin_amdgcn_mfma_f32_16x16x32_bf16(fa[i], fb[j], acc[i][j], 0, 0, 0); \
    __builtin_amdgcn_s_setprio(0); }

    GSTAGE(0, 0); GSTAGE(1, 1); GSTAGE(2, 2);
    for (int kt = 0; kt < NT - 3; ++kt) {
        GSTAGE((kt + 3) & 3, kt + 3);
        PIPE_WAIT(6);
        GCOMP(kt & 3);
        PIPE_END();
    }
    PIPE_WAIT(4); GCOMP((NT - 3) & 3); PIPE_END();
    PIPE_WAIT(2); GCOMP((NT - 2) & 3); PIPE_END();
    PIPE_WAIT(0); GCOMP((NT - 1) & 3);

    const bool mirror = (r0 != r1);
    #pragma unroll
    for (int i = 0; i < 2; ++i) {
        const int rA = r0 + (w >> 1) * 32 + i * 16 + (l >> 4) * 4;
        #pragma unroll
        for (int j = 0; j < 2; ++j) {
            const int rB = r1 + (w & 1) * 32 + j * 16 + (l & 15);
            #pragma unroll
            for (int rg = 0; rg < 4; ++rg) {
                atomicAdd(&G[(size_t)(rA + rg) * RR + rB], acc[i][j][rg]);
                if (mirror)
                    atomicAdd(&G[(size_t)rB * RR + rA + rg], acc[i][j][rg]);
            }
        }
    }
}

// ---------------------------------------------------------------------------
// K3: normsq[b] += slice-sum of ev_r ev_r' Gu[r,r'] Gv[r,r']
// ---------------------------------------------------------------------------
__global__ __launch_bounds__(256) void k_norm(const float* __restrict__ Gu,
                                              const float* __restrict__ Gv,
                                              const float* __restrict__ dd,
                                              const int* __restrict__ dirs,
                                              float* __restrict__ normsq) {
    const int b = blockIdx.x, sl = blockIdx.y;
    __shared__ float evs[RR];
    __shared__ float red[256];
    const int t = threadIdx.x;
    const float* ev = dd + (size_t)dirs[b] * RR;
    for (int i = t; i < RR; i += 256) evs[i] = ev[i];
    __syncthreads();
    float acc = 0.f;
    const int base = sl * (RR * RR / 8);
    for (int p = base + t; p < base + RR * RR / 8; p += 256) {
        int r = p >> 9, r2 = p & 511;
        acc += Gu[p] * Gv[p] * evs[r] * evs[r2];
    }
    red[t] = acc;
    __syncthreads();
    for (int o = 128; o > 0; o >>= 1) {
        if (t < o) red[t] += red[t + o];
        __syncthreads();
    }
    if (t == 0) atomicAdd(&normsq[b], red[0]);
}

// ---------------------------------------------------------------------------
// K4: MFMA delta-GEMM + weight build + demod partials.  (round-11-proven)
// 128x128 tile, 3-buffer ring (48 KB), vmcnt(8), setprio.
// Epilogue: LDS-bounce with stride 138 (bank-conflict-free) ->
// coalesced wgtb/s reads, dense 16B/lane Wf stores.
// ---------------------------------------------------------------------------
__global__ __launch_bounds__(256) void k_build_mfma(
        const __hip_bfloat16* __restrict__ ubf,   // [MM][RR]
        const __hip_bfloat16* __restrict__ vt,    // [B][COUT][RR]
        const __hip_bfloat16* __restrict__ wgtb,  // [COUT][9][512] bf16
        const float* __restrict__ s,              // [B][CIN]
        const float* __restrict__ normsq,
        const float* __restrict__ shifts,
        __hip_bfloat16* __restrict__ Wf,          // [B][MT][COUT][32] swizzled
        float* __restrict__ demodsq) {
    const int m0  = blockIdx.x * 128;
    const int co0 = blockIdx.y * 128;
    const int b   = blockIdx.z;
    __shared__ __align__(16) char bLDS[3 * 16384];   // 48 KB (ring; reused by epilogue)
    const int t = threadIdx.x;
    const int w = t >> 6, l = t & 63;
    const int row = t >> 2, ls = t & 3;
    const int sg  = ls ^ ((row >> 1) & 3);

    const char* ua  = (const char*)(ubf + (size_t)(m0 + row) * RR) + sg * 16;
    const char* ua2 = ua + (size_t)64 * RR * 2;
    const char* va  = (const char*)(vt + ((size_t)b * COUT + co0 + row) * RR) + sg * 16;
    const char* va2 = va + (size_t)64 * RR * 2;
    const int dst0 = t * 16;

    f32x4 acc[4][4];
    #pragma unroll
    for (int i = 0; i < 4; ++i)
        #pragma unroll
        for (int j = 0; j < 4; ++j) acc[i][j] = (f32x4){0.f, 0.f, 0.f, 0.f};

#define BSTAGE(Ab_, kt) { const int rb = (kt) * 64;                          \
    gload_lds16(ua  + rb, (Ab_) + dst0);                                     \
    gload_lds16(ua2 + rb, (Ab_) + dst0 + 4096);                              \
    gload_lds16(va  + rb, (Ab_) + 8192 + dst0);                              \
    gload_lds16(va2 + rb, (Ab_) + 8192 + dst0 + 4096); }

#define BCOMPUTE(Ab_) { const char* Bb_ = (Ab_) + 8192;                      \
    bf16x8 fa[4], fb[4];                                                     \
    const int sl = (l >> 4) << 4;                                            \
    const int ar = (w >> 1) * 64 + (l & 15);                                 \
    const int br = (w & 1) * 64 + (l & 15);                                  \
    _Pragma("unroll") for (int i = 0; i < 4; ++i) {                          \
        int r = ar + i * 16;                                                 \
        fa[i] = *(const bf16x8*)((Ab_) + r * 64 + (sl ^ (((r >> 1) & 3) << 4))); \
        int q = br + i * 16;                                                 \
        fb[i] = *(const bf16x8*)(Bb_ + q * 64 + (sl ^ (((q >> 1) & 3) << 4))); } \
    __builtin_amdgcn_s_setprio(1);                                           \
    _Pragma("unroll") for (int i = 0; i < 4; ++i)                            \
        _Pragma("unroll") for (int j = 0; j < 4; ++j)                        \
            acc[i][j] = __builtin_amdgcn_mfma_f32_16x16x32_bf16(fa[i], fb[j], acc[i][j], 0, 0, 0); \
    __builtin_amdgcn_s_setprio(0); }

    char* cbuf = bLDS;
    char* nbuf = bLDS + 16384;
    char* sbuf = bLDS + 32768;
    BSTAGE(cbuf, 0); BSTAGE(nbuf, 1);
    for (int kt = 0; kt < 14; ++kt) {
        BSTAGE(sbuf, kt + 2);
        PIPE_WAIT(8);
        BCOMPUTE(cbuf);
        PIPE_END();
        char* tmp = cbuf; cbuf = nbuf; nbuf = sbuf; sbuf = tmp;
    }
    PIPE_WAIT(4); BCOMPUTE(cbuf); PIPE_END();   // kt=14
    PIPE_WAIT(0); BCOMPUTE(nbuf);               // kt=15

    // ---- epilogue: LDS-bounce, stride 138 (276 B -> bank stride 69, odd)
    __syncthreads();
    {
        __hip_bfloat16* D = (__hip_bfloat16*)bLDS;    // [128 co][138 m-slots] = 35.3 KB
        float* red = (float*)(bLDS + 35328);          // 128 floats
        const int co_l0 = (w & 1) * 64 + (l & 15);
        const int m_l0  = (w >> 1) * 64 + (l >> 4) * 4;
        #pragma unroll
        for (int i = 0; i < 4; ++i) {
            #pragma unroll
            for (int j = 0; j < 4; ++j) {
                __hip_bfloat16 d4[4] = {
                    __float2bfloat16(acc[i][j][0]), __float2bfloat16(acc[i][j][1]),
                    __float2bfloat16(acc[i][j][2]), __float2bfloat16(acc[i][j][3])};
                *(ushort4*)&D[(co_l0 + j * 16) * 138 + m_l0 + i * 16] = *(const ushort4*)d4;
            }
        }
        if (t < 128) red[t] = 0.f;
        __syncthreads();
        const float cf = shifts[b] / fmaxf(sqrtf(normsq[b]), 1e-12f);
        const int kkc = m0 >> 9;
        const int mt0 = m0 >> 5;
        const int ci0 = m0 & 511;
        #pragma unroll
        for (int p = 0; p < 8; ++p) {
            const int idx  = p * 256 + t;
            const int oct  = idx & 3;
            const int mtl  = (idx >> 2) & 3;
            const int co_l = idx >> 4;
            const int co   = co0 + co_l;
            const int swz  = ((co >> 1) & 3) << 3;
            const int m_l  = mtl * 32 + ((oct * 8) ^ swz);
            bf16x8 dv = *(const bf16x8*)&D[co_l * 138 + m_l];
            const int ci = ci0 + m_l;
            bf16x8 wv = *(const bf16x8*)&wgtb[((size_t)co * KK + kkc) * 512 + ci];
            float4 s0 = *(const float4*)&s[b * CIN + ci];
            float4 s1 = *(const float4*)&s[b * CIN + ci + 4];
            float sv[8] = {s0.x, s0.y, s0.z, s0.w, s1.x, s1.y, s1.z, s1.w};
            __hip_bfloat16 vb[8];
            float psum = 0.f;
            #pragma unroll
            for (int e = 0; e < 8; ++e) {
                short sd = dv[e], sw = wv[e];
                float dd = __bfloat162float(*(__hip_bfloat16*)&sd);
                float ww = __bfloat162float(*(__hip_bfloat16*)&sw);
                float v = SCALE_F * (ww + cf * dd) * sv[e];
                vb[e] = __float2bfloat16(v);
                psum += v * v;
            }
            *(bf16x8*)&Wf[(((size_t)b * MT + mt0 + mtl) * COUT + co) * 32 + oct * 8]
                = *(const bf16x8*)vb;
            atomicAdd(&red[co_l], psum);
        }
        __syncthreads();
        if (t < 128) atomicAdd(&demodsq[b * COUT + co0 + t], red[t]);
    }
}

// ---------------------------------------------------------------------------
// K5: grouped conv as MFMA implicit GEMM. 4-buffer pipeline + XCD swizzle
// + incremental B-addressing + setprio.
// ---------------------------------------------------------------------------
__global__ __launch_bounds__(256) void k_conv_mfma(
        const __hip_bfloat16* __restrict__ Wf,     // [b][mt][co][32] swizzled
        const __hip_bfloat16* __restrict__ xh,     // [b][34][34][512]
        const float* __restrict__ demodsq,
        float* __restrict__ out) {
    const int id  = blockIdx.x;
    const int swb = (id & 7) * 64 + (id >> 3);
    const int p0  = (swb & 7) * 128;
    const int co0 = ((swb >> 3) & 3) * 128;
    const int b   = swb >> 5;
    __shared__ __align__(16) char cLDS[4 * 16384];   // 64 KB
    const int t = threadIdx.x;
    const int w = t >> 6, l = t & 63;

    const char* wsrc0 = (const char*)(Wf + (((size_t)b * MT) * COUT + co0) * 32);
    const int lq = l >> 2;
    const int ls = l & 3;
    const int off0 = t * 16;

    const __hip_bfloat16* bsrc0;
    const __hip_bfloat16* bsrc1;

    f32x4 acc[4][4];
    #pragma unroll
    for (int i = 0; i < 4; ++i)
        #pragma unroll
        for (int j = 0; j < 4; ++j) acc[i][j] = (f32x4){0.f, 0.f, 0.f, 0.f};

#define CADDR(mt) {                                                          \
    const int kk_ = (mt) >> 4;                                               \
    const int dy_ = kk_ / 3 - 1, dx_ = kk_ % 3 - 1;                          \
    { int p_l_ = w * 16 + lq; int P_ = p0 + p_l_;                            \
      int yy_ = (P_ >> 5) + dy_ + 1; int xx_ = (P_ & 31) + dx_ + 1;          \
      int sg_ = ls ^ ((p_l_ >> 1) & 3);                                      \
      bsrc0 = xh + (((size_t)b * 34 + yy_) * 34 + xx_) * CIN + sg_ * 8; }    \
    { int p_l_ = 64 + w * 16 + lq; int P_ = p0 + p_l_;                       \
      int yy_ = (P_ >> 5) + dy_ + 1; int xx_ = (P_ & 31) + dx_ + 1;          \
      int sg_ = ls ^ ((p_l_ >> 1) & 3);                                      \
      bsrc1 = xh + (((size_t)b * 34 + yy_) * 34 + xx_) * CIN + sg_ * 8; } }

#define CSTAGE(Ab_, mt) {                                                    \
    if (((mt) & 15) == 0) { CADDR(mt); } else { bsrc0 += 32; bsrc1 += 32; }  \
    const char* wa_ = wsrc0 + (size_t)(mt) * (COUT * 32 * 2);                \
    gload_lds16(wa_ + off0,        (Ab_) + off0);                            \
    gload_lds16(wa_ + off0 + 4096, (Ab_) + off0 + 4096);                     \
    gload_lds16(bsrc0, (Ab_) + 8192 + w * 1024 + l * 16);                    \
    gload_lds16(bsrc1, (Ab_) + 8192 + 4096 + w * 1024 + l * 16); }

#define CCOMPUTE(Ab_) { const char* Bb_ = (Ab_) + 8192;                      \
    bf16x8 fa[4], fb[4];                                                     \
    const int sl = (l >> 4) << 4;                                            \
    const int ar = (w >> 1) * 64 + (l & 15);                                 \
    const int br = (w & 1) * 64 + (l & 15);                                  \
    _Pragma("unroll") for (int i = 0; i < 4; ++i) {                          \
        int r = ar + i * 16;                                                 \
        fa[i] = *(const bf16x8*)((Ab_) + r * 64 + (sl ^ (((r >> 1) & 3) << 4))); \
        int q = br + i * 16;                                                 \
        fb[i] = *(const bf16x8*)(Bb_ + q * 64 + (sl ^ (((q >> 1) & 3) << 4))); } \
    __builtin_amdgcn_s_setprio(1);                                           \
    _Pragma("unroll") for (int i = 0; i < 4; ++i)                            \
        _Pragma("unroll") for (int j = 0; j < 4; ++j)                        \
            acc[i][j] = __builtin_amdgcn_mfma_f32_16x16x32_bf16(fa[i], fb[j], acc[i][j], 0, 0, 0); \
    __builtin_amdgcn_s_setprio(0); }

    CSTAGE(cLDS, 0); CSTAGE(cLDS + 16384, 1); CSTAGE(cLDS + 32768, 2);
    for (int mt = 0; mt < MT - 3; ++mt) {
        CSTAGE(cLDS + ((mt + 3) & 3) * 16384, mt + 3);
        PIPE_WAIT(12);
        CCOMPUTE(cLDS + (mt & 3) * 16384);
        PIPE_END();
    }
    PIPE_WAIT(8); CCOMPUTE(cLDS + ((MT - 3) & 3) * 16384); PIPE_END();
    PIPE_WAIT(4); CCOMPUTE(cLDS + ((MT - 2) & 3) * 16384); PIPE_END();
    PIPE_WAIT(0); CCOMPUTE(cLDS + ((MT - 1) & 3) * 16384);

    const float* dmrow = demodsq + b * COUT;
    #pragma unroll
    for (int i = 0; i < 4; ++i) {
        int co = co0 + (w >> 1) * 64 + i * 16 + (l >> 4) * 4;
        #pragma unroll
        for (int r = 0; r < 4; ++r) {
            float dm = rsqrtf(dmrow[co + r] + 1e-8f);
            #pragma unroll
            for (int j = 0; j < 4; ++j) {
                int p = p0 + (w & 1) * 64 + j * 16 + (l & 15);
                out[((size_t)b * COUT + co + r) * HW + p] = acc[i][j][r] * dm;
            }
        }
    }
}

// ---------------------------------------------------------------------------
extern "C" void kernel_launch(void* const* d_in, const int* in_sizes, int n_in,
                              void* d_out, int out_size, void* d_ws, size_t ws_size,
                              hipStream_t stream) {
    const float* x         = (const float*)d_in[0];
    const float* style     = (const float*)d_in[1];
    const float* mw        = (const float*)d_in[2];
    const float* mb        = (const float*)d_in[3];
    const float* weight    = (const float*)d_in[4];
    const float* u         = (const float*)d_in[5];
    const float* vh        = (const float*)d_in[6];
    const float* dir_delta = (const float*)d_in[7];
    const float* shifts    = (const float*)d_in[8];
    const int*   dirs      = (const int*)d_in[9];
    float* out = (float*)d_out;

    // ---- ws layout (high-water 94,568,448 B — round-4-proven offsets kept)
    char* base = (char*)d_ws;
    float* s       = (float*)(base);                    // 32 KB
    float* demodsq = (float*)(base + 32768);            // 32 KB
    float* normsq  = (float*)(base + 65536);            // 64 B (zero1 spans both)
    char* X = base + 131072;
    __hip_bfloat16* xh = (__hip_bfloat16*)(X);                 // 18.94 MB
    __hip_bfloat16* Wf = (__hip_bfloat16*)(X + 18939904);      // 75.5 MB

    // ---- pre-conv scratch lives in d_out (25.2 MB of 33.55 MB; all dead
    // before k_conv_mfma, which overwrites every byte of d_out each call)
    char* O = (char*)d_out;
    __hip_bfloat16* ubf  = (__hip_bfloat16*)(O);               // 4.72 MB
    __hip_bfloat16* ubfT = (__hip_bfloat16*)(O + 4718592);     // 4.72 MB
    __hip_bfloat16* vt   = (__hip_bfloat16*)(O + 9437184);     // 8.39 MB
    __hip_bfloat16* wgtb = (__hip_bfloat16*)(O + 17825792);    // 4.72 MB
    __hip_bfloat16* vhb  = (__hip_bfloat16*)(O + 22544384);    // 0.52 MB
    float*          Gu   = (float*)(O + 23068672);             // 1 MB
    float*          Gv   = (float*)(O + 24117248);             // 1 MB

    k_prep      <<<dim3(3061),      256, 0, stream>>>(style, mw, mb, s,
                                                      u, ubf, ubfT, vh, vhb,
                                                      dir_delta, dirs, vt,
                                                      weight, wgtb, x, xh,
                                                      demodsq, Gu);
    k_gram2     <<<dim3(36, 11),    256, 0, stream>>>(ubfT, vhb, Gu, Gv);
    k_norm      <<<dim3(BB, 8),     256, 0, stream>>>(Gu, Gv, dir_delta, dirs, normsq);
    k_build_mfma<<<dim3(36, 4, BB), 256, 0, stream>>>(ubf, vt, wgtb, s, normsq, shifts, Wf, demodsq);
    k_conv_mfma <<<dim3(512),       256, 0, stream>>>(Wf, xh, demodsq, out);
}

// Round 14
// 231.011 us; speedup vs baseline: 1.1337x; 1.1337x over previous
//
#include <hip/hip_runtime.h>
#include <hip/hip_bf16.h>

// Problem constants
#define BB   16
#define CIN  512
#define COUT 512
#define KS   3
#define KK   9
#define HH   32
#define WW   32
#define HW   1024
#define SDIM 512
#define RR   512
#define MM   4608               // KK*CIN; m = kk*512 + ci
#define MT   144                // MM/32 k-tiles
#define SCALE_F 0.014731391274719738f  // 1/sqrt(4608)

typedef __attribute__((ext_vector_type(8))) short bf16x8;
typedef __attribute__((ext_vector_type(4))) float f32x4;

__device__ __forceinline__ void gload_lds16(const void* g, void* l) {
    __builtin_amdgcn_global_load_lds(
        (const __attribute__((address_space(1))) unsigned int*)g,
        (__attribute__((address_space(3))) unsigned int*)l,
        16, 0, 0);
}

#define PIPE_WAIT(N) do {                                            \
    asm volatile("s_waitcnt vmcnt(" #N ")" ::: "memory");            \
    __builtin_amdgcn_s_barrier();                                    \
    __builtin_amdgcn_sched_barrier(0); } while (0)
#define PIPE_END() do {                                              \
    __builtin_amdgcn_sched_barrier(0);                               \
    __builtin_amdgcn_s_barrier(); } while (0)

// ---------------------------------------------------------------------------
// K_prep: ONE kernel for every input-only transform (block-uniform sections).
//  [0,32)      : s[b,ci] = style . mw^T + mb
//  [32,608)    : ubf[m][r]=bf16(u), ubfT[r][m]=bf16(u)   (72x8 tiles)
//  [608,736)   : vhb = bf16(vh)
//  [736,1760)  : vt[b][co][r] = bf16(ev_b[r]*vh[r][co])
//  [1760,2272) : wgtb[co][kk][ci] = bf16(weight[co][ci][kk])
//  [2272,2784) : xpose interior (x -> xh NHWC bf16)
//  [2784,2800) : xh halo zero (one block per b)
//  [2800,2805) : zero demodsq+normsq (8208 floats)
//  [2805,3061) : zero Gu+Gv (524288 floats)
// ---------------------------------------------------------------------------
__global__ __launch_bounds__(256) void k_prep(
        const float* __restrict__ style, const float* __restrict__ mw,
        const float* __restrict__ mb, float* __restrict__ s,
        const float* __restrict__ u, __hip_bfloat16* __restrict__ ub,
        __hip_bfloat16* __restrict__ uT,
        const float* __restrict__ vh, __hip_bfloat16* __restrict__ vhb,
        const float* __restrict__ dd, const int* __restrict__ dirs,
        __hip_bfloat16* __restrict__ vt,
        const float* __restrict__ wgt, __hip_bfloat16* __restrict__ wgtb,
        const float* __restrict__ x, __hip_bfloat16* __restrict__ xh,
        float* __restrict__ zero1, float* __restrict__ zero2) {
    const int id = blockIdx.x;
    const int t = threadIdx.x;
    __shared__ __align__(16) char shbuf[18432];

    if (id < 32) {
        int idx = id * 256 + t;
        int b = idx >> 9, ci = idx & 511;
        const float* st = style + (size_t)b * SDIM;
        const float* w  = mw + (size_t)ci * SDIM;
        float acc = 0.f;
        for (int d = 0; d < SDIM; d += 4)
            acc += st[d]*w[d] + st[d+1]*w[d+1] + st[d+2]*w[d+2] + st[d+3]*w[d+3];
        s[idx] = acc + mb[ci];
    } else if (id < 608) {
        __hip_bfloat16 (*tile)[80] = (__hip_bfloat16(*)[80])shbuf;
        const int bx = id - 32;
        const int m0 = (bx % 72) * 64, r0 = (bx / 72) * 64;
        const int ml = t >> 4, rl4 = (t & 15) * 4;
        #pragma unroll
        for (int p = 0; p < 4; ++p) {
            int m_l = ml + p * 16;
            float4 v = *(const float4*)&u[(size_t)(m0 + m_l) * RR + r0 + rl4];
            __hip_bfloat16 b4[4] = {__float2bfloat16(v.x), __float2bfloat16(v.y),
                                    __float2bfloat16(v.z), __float2bfloat16(v.w)};
            *(ushort4*)&ub[(size_t)(m0 + m_l) * RR + r0 + rl4] = *(const ushort4*)b4;
            tile[rl4+0][m_l] = b4[0];
            tile[rl4+1][m_l] = b4[1];
            tile[rl4+2][m_l] = b4[2];
            tile[rl4+3][m_l] = b4[3];
        }
        __syncthreads();
        const int cl = t >> 2, rg = (t & 3) * 16;
        __hip_bfloat16* dst = uT + (size_t)(r0 + cl) * MM + m0 + rg;
        *(bf16x8*)dst       = *(const bf16x8*)&tile[cl][rg];
        *(bf16x8*)(dst + 8) = *(const bf16x8*)&tile[cl][rg + 8];
    } else if (id < 736) {
        size_t i = ((size_t)(id - 608) * 256 + t) * 8;
        float4 a = *(const float4*)(vh + i);
        float4 b = *(const float4*)(vh + i + 4);
        __hip_bfloat16 o[8] = {
            __float2bfloat16(a.x), __float2bfloat16(a.y),
            __float2bfloat16(a.z), __float2bfloat16(a.w),
            __float2bfloat16(b.x), __float2bfloat16(b.y),
            __float2bfloat16(b.z), __float2bfloat16(b.w)};
        *(bf16x8*)(vhb + i) = *(const bf16x8*)o;
    } else if (id < 1760) {
        __hip_bfloat16 (*tile)[80] = (__hip_bfloat16(*)[80])shbuf;
        const int vid = id - 736;
        const int co0 = (vid & 7) * 64, r0 = ((vid >> 3) & 7) * 64, b = vid >> 6;
        const float* ev = dd + (size_t)dirs[b] * RR;
        int tc4 = (t & 15) * 4, tr = t >> 4;
        #pragma unroll
        for (int pass = 0; pass < 4; ++pass) {
            int r = tr + pass * 16;
            float e = ev[r0 + r];
            float4 v = *(const float4*)&vh[(size_t)(r0 + r) * COUT + co0 + tc4];
            tile[tc4+0][r] = __float2bfloat16(v.x * e);
            tile[tc4+1][r] = __float2bfloat16(v.y * e);
            tile[tc4+2][r] = __float2bfloat16(v.z * e);
            tile[tc4+3][r] = __float2bfloat16(v.w * e);
        }
        __syncthreads();
        int cl = t >> 2, rg = (t & 3) * 16;
        __hip_bfloat16* dst = vt + ((size_t)b * COUT + co0 + cl) * RR + r0 + rg;
        *(bf16x8*)dst       = *(const bf16x8*)&tile[cl][rg];
        *(bf16x8*)(dst + 8) = *(const bf16x8*)&tile[cl][rg + 8];
    } else if (id < 2272) {
        float* lw = (float*)shbuf;
        const int co = id - 1760;
        for (int e = t; e < MM; e += 256) lw[e] = wgt[(size_t)co * MM + e];
        __syncthreads();
        for (int e0 = t * 8; e0 < MM; e0 += 2048) {
            int kk = e0 >> 9, ci = e0 & 511;
            __hip_bfloat16 o[8];
            #pragma unroll
            for (int q = 0; q < 8; ++q)
                o[q] = __float2bfloat16(lw[(ci + q) * KK + kk]);
            *(bf16x8*)&wgtb[(size_t)co * MM + e0] = *(const bf16x8*)o;
        }
    } else if (id < 2784) {
        __hip_bfloat16 (*tileT)[72] = (__hip_bfloat16(*)[72])shbuf;
        const int xid = id - 2272;
        const int b = xid >> 5;
        const int y = xid & 31;
        for (int c0 = 0; c0 < CIN; c0 += 64) {
            int ci_l = t >> 2, xq = (t & 3) * 8;
            const float* src = x + (((size_t)(b * CIN + c0 + ci_l)) * HH + y) * WW + xq;
            float4 v0 = *(const float4*)src;
            float4 v1 = *(const float4*)(src + 4);
            __syncthreads();
            tileT[xq+0][ci_l] = __float2bfloat16(v0.x);
            tileT[xq+1][ci_l] = __float2bfloat16(v0.y);
            tileT[xq+2][ci_l] = __float2bfloat16(v0.z);
            tileT[xq+3][ci_l] = __float2bfloat16(v0.w);
            tileT[xq+4][ci_l] = __float2bfloat16(v1.x);
            tileT[xq+5][ci_l] = __float2bfloat16(v1.y);
            tileT[xq+6][ci_l] = __float2bfloat16(v1.z);
            tileT[xq+7][ci_l] = __float2bfloat16(v1.w);
            __syncthreads();
            int x_l = t >> 3, cg = (t & 7) * 8;
            bf16x8 o = *(const bf16x8*)&tileT[x_l][cg];
            *(bf16x8*)&xh[(((size_t)b * 34 + y + 1) * 34 + (x_l + 1)) * CIN + c0 + cg] = o;
        }
    } else if (id < 2800) {
        const int b = id - 2784;
        for (int c = t; c < 132 * 64; c += 256) {
            int cell = c >> 6, part = c & 63;
            int yy, xx;
            if (cell < 34)      { yy = 0;  xx = cell; }
            else if (cell < 68) { yy = 33; xx = cell - 34; }
            else if (cell < 100){ yy = cell - 68 + 1;  xx = 0; }
            else                { yy = cell - 100 + 1; xx = 33; }
            bf16x8 z = {0,0,0,0,0,0,0,0};
            *(bf16x8*)&xh[(((size_t)b * 34 + yy) * 34 + xx) * CIN + part * 8] = z;
        }
    } else if (id < 2805) {
        int idx = (id - 2800) * 2048 + t * 8;
        if (idx < 8208) {
            float4 z = {0.f, 0.f, 0.f, 0.f};
            *(float4*)(zero1 + idx) = z;
            *(float4*)(zero1 + idx + 4) = z;
        }
    } else {
        int idx = (id - 2805) * 2048 + t * 8;
        float4 z = {0.f, 0.f, 0.f, 0.f};
        *(float4*)(zero2 + idx) = z;
        *(float4*)(zero2 + idx + 4) = z;
    }
}

// ---------------------------------------------------------------------------
// K2: merged Gram kernel (round-11 form). z<9: Gu slice; z>=9: Gv slice.
// 64x64 tile, 4 waves (2x2 of 32x32), BK=32, 4-buffer pipeline, atomic epi.
// ---------------------------------------------------------------------------
__global__ __launch_bounds__(256) void k_gram2(
        const __hip_bfloat16* __restrict__ uT,    // [RR][MM]
        const __hip_bfloat16* __restrict__ vhb,   // [RR][COUT]
        float* __restrict__ Gu, float* __restrict__ Gv) {
    const int r0 = blockIdx.x * 64, r1 = blockIdx.y * 64;
    const int z  = blockIdx.z;
    const bool isGu = (z < 9);
    const __hip_bfloat16* src = isGu ? uT : vhb;
    const int ldb   = (isGu ? MM : COUT) * 2;          // row stride bytes
    const int koff  = isGu ? z * 1024 : (z - 9) * 512; // k offset bytes
    const int NT    = isGu ? 16 : 8;
    float* G = isGu ? Gu : Gv;

    __shared__ __align__(16) char gLDS[4 * 8192];      // 32 KB
    const int t = threadIdx.x;
    const int w = t >> 6, l = t & 63;
    const int row = t >> 2, ls = t & 3;
    const int sg = ls ^ ((row >> 1) & 3);

    const char* sa = (const char*)src + (size_t)(r0 + row) * ldb + koff + sg * 16;
    const char* sb = (const char*)src + (size_t)(r1 + row) * ldb + koff + sg * 16;

    f32x4 acc[2][2];
    #pragma unroll
    for (int i = 0; i < 2; ++i)
        #pragma unroll
        for (int j = 0; j < 2; ++j) acc[i][j] = (f32x4){0.f, 0.f, 0.f, 0.f};

#define GSTAGE(bn, kt) { char* Gb_ = gLDS + (bn) * 8192;                     \
    gload_lds16(sa + (kt) * 64, Gb_ + t * 16);                               \
    gload_lds16(sb + (kt) * 64, Gb_ + 4096 + t * 16); }

#define GCOMP(bn) { const char* Ab_ = gLDS + (bn) * 8192;                    \
    const char* Bb_ = Ab_ + 4096;                                            \
    bf16x8 fa[2], fb[2];                                                     \
    const int sl = (l >> 4) << 4;                                            \
    const int ar = (w >> 1) * 32 + (l & 15);                                 \
    const int br = (w & 1) * 32 + (l & 15);                                  \
    _Pragma("unroll") for (int i = 0; i < 2; ++i) {                          \
        int r = ar + i * 16;                                                 \
        fa[i] = *(const bf16x8*)(Ab_ + r * 64 + (sl ^ (((r >> 1) & 3) << 4))); \
        int q = br + i * 16;                                                 \
        fb[i] = *(const bf16x8*)(Bb_ + q * 64 + (sl ^ (((q >> 1) & 3) << 4))); } \
    __builtin_amdgcn_s_setprio(1);                                           \
    _Pragma("unroll") for (int i = 0; i < 2; ++i)                            \
        _Pragma("unroll") for (int j = 0; j < 2; ++j)                        \
            acc[i][j] = __builtin_amdgcn_mfma_f32_16x16x32_bf16(fa[i], fb[j], acc[i][j], 0, 0, 0); \
    __builtin_amdgcn_s_setprio(0); }

    GSTAGE(0, 0); GSTAGE(1, 1); GSTAGE(2, 2);
    for (int kt = 0; kt < NT - 3; ++kt) {
        GSTAGE((kt + 3) & 3, kt + 3);
        PIPE_WAIT(6);
        GCOMP(kt & 3);
        PIPE_END();
    }
    PIPE_WAIT(4); GCOMP((NT - 3) & 3); PIPE_END();
    PIPE_WAIT(2); GCOMP((NT - 2) & 3); PIPE_END();
    PIPE_WAIT(0); GCOMP((NT - 1) & 3);

    #pragma unroll
    for (int i = 0; i < 2; ++i) {
        const int rA = r0 + (w >> 1) * 32 + i * 16 + (l >> 4) * 4;
        #pragma unroll
        for (int j = 0; j < 2; ++j) {
            const int rB = r1 + (w & 1) * 32 + j * 16 + (l & 15);
            #pragma unroll
            for (int rg = 0; rg < 4; ++rg)
                atomicAdd(&G[(size_t)(rA + rg) * RR + rB], acc[i][j][rg]);
        }
    }
}

// ---------------------------------------------------------------------------
// K3: normsq[b] += slice-sum of ev_r ev_r' Gu[r,r'] Gv[r,r']
// ---------------------------------------------------------------------------
__global__ __launch_bounds__(256) void k_norm(const float* __restrict__ Gu,
                                              const float* __restrict__ Gv,
                                              const float* __restrict__ dd,
                                              const int* __restrict__ dirs,
                                              float* __restrict__ normsq) {
    const int b = blockIdx.x, sl = blockIdx.y;
    __shared__ float evs[RR];
    __shared__ float red[256];
    const int t = threadIdx.x;
    const float* ev = dd + (size_t)dirs[b] * RR;
    for (int i = t; i < RR; i += 256) evs[i] = ev[i];
    __syncthreads();
    float acc = 0.f;
    const int base = sl * (RR * RR / 8);
    for (int p = base + t; p < base + RR * RR / 8; p += 256) {
        int r = p >> 9, r2 = p & 511;
        acc += Gu[p] * Gv[p] * evs[r] * evs[r2];
    }
    red[t] = acc;
    __syncthreads();
    for (int o = 128; o > 0; o >>= 1) {
        if (t < o) red[t] += red[t + o];
        __syncthreads();
    }
    if (t == 0) atomicAdd(&normsq[b], red[0]);
}

// ---------------------------------------------------------------------------
// K4: MFMA delta-GEMM + weight build + demod partials.  (round-11 structure)
// 128x128 tile, 3-buffer ring (48 KB), vmcnt(8), setprio.
// Epilogue: LDS-bounce with 16B-granule XOR swizzle at stride 256 B —
// fully aligned AND 2-way-max bank access (free).
// ---------------------------------------------------------------------------
__global__ __launch_bounds__(256) void k_build_mfma(
        const __hip_bfloat16* __restrict__ ubf,   // [MM][RR]
        const __hip_bfloat16* __restrict__ vt,    // [B][COUT][RR]
        const __hip_bfloat16* __restrict__ wgtb,  // [COUT][9][512] bf16
        const float* __restrict__ s,              // [B][CIN]
        const float* __restrict__ normsq,
        const float* __restrict__ shifts,
        __hip_bfloat16* __restrict__ Wf,          // [B][MT][COUT][32] swizzled
        float* __restrict__ demodsq) {
    const int m0  = blockIdx.x * 128;
    const int co0 = blockIdx.y * 128;
    const int b   = blockIdx.z;
    __shared__ __align__(16) char bLDS[3 * 16384];   // 48 KB (ring; reused by epilogue)
    const int t = threadIdx.x;
    const int w = t >> 6, l = t & 63;
    const int row = t >> 2, ls = t & 3;
    const int sg  = ls ^ ((row >> 1) & 3);

    const char* ua  = (const char*)(ubf + (size_t)(m0 + row) * RR) + sg * 16;
    const char* ua2 = ua + (size_t)64 * RR * 2;
    const char* va  = (const char*)(vt + ((size_t)b * COUT + co0 + row) * RR) + sg * 16;
    const char* va2 = va + (size_t)64 * RR * 2;
    const int dst0 = t * 16;

    f32x4 acc[4][4];
    #pragma unroll
    for (int i = 0; i < 4; ++i)
        #pragma unroll
        for (int j = 0; j < 4; ++j) acc[i][j] = (f32x4){0.f, 0.f, 0.f, 0.f};

#define BSTAGE(Ab_, kt) { const int rb = (kt) * 64;                          \
    gload_lds16(ua  + rb, (Ab_) + dst0);                                     \
    gload_lds16(ua2 + rb, (Ab_) + dst0 + 4096);                              \
    gload_lds16(va  + rb, (Ab_) + 8192 + dst0);                              \
    gload_lds16(va2 + rb, (Ab_) + 8192 + dst0 + 4096); }

#define BCOMPUTE(Ab_) { const char* Bb_ = (Ab_) + 8192;                      \
    bf16x8 fa[4], fb[4];                                                     \
    const int sl = (l >> 4) << 4;                                            \
    const int ar = (w >> 1) * 64 + (l & 15);                                 \
    const int br = (w & 1) * 64 + (l & 15);                                  \
    _Pragma("unroll") for (int i = 0; i < 4; ++i) {                          \
        int r = ar + i * 16;                                                 \
        fa[i] = *(const bf16x8*)((Ab_) + r * 64 + (sl ^ (((r >> 1) & 3) << 4))); \
        int q = br + i * 16;                                                 \
        fb[i] = *(const bf16x8*)(Bb_ + q * 64 + (sl ^ (((q >> 1) & 3) << 4))); } \
    __builtin_amdgcn_s_setprio(1);                                           \
    _Pragma("unroll") for (int i = 0; i < 4; ++i)                            \
        _Pragma("unroll") for (int j = 0; j < 4; ++j)                        \
            acc[i][j] = __builtin_amdgcn_mfma_f32_16x16x32_bf16(fa[i], fb[j], acc[i][j], 0, 0, 0); \
    __builtin_amdgcn_s_setprio(0); }

    char* cbuf = bLDS;
    char* nbuf = bLDS + 16384;
    char* sbuf = bLDS + 32768;
    BSTAGE(cbuf, 0); BSTAGE(nbuf, 1);
    for (int kt = 0; kt < 14; ++kt) {
        BSTAGE(sbuf, kt + 2);
        PIPE_WAIT(8);
        BCOMPUTE(cbuf);
        PIPE_END();
        char* tmp = cbuf; cbuf = nbuf; nbuf = sbuf; sbuf = tmp;
    }
    PIPE_WAIT(4); BCOMPUTE(cbuf); PIPE_END();   // kt=14
    PIPE_WAIT(0); BCOMPUTE(nbuf);               // kt=15

    // ---- epilogue: LDS-bounce, stride 256 B + 16B-granule XOR swizzle
    // byte(co, m) = co*256 + ((2m) ^ ((co&15)<<4))  — aligned, conflict-free
    __syncthreads();
    {
        char* Db = bLDS;                              // 128 x 256 B = 32 KB
        float* red = (float*)(bLDS + 32768);          // 128 floats
        const int co_l0 = (w & 1) * 64 + (l & 15);
        const int m_l0  = (w >> 1) * 64 + (l >> 4) * 4;
        const int key   = (l & 15) << 4;              // == (co&15)<<4 for all j
        #pragma unroll
        for (int i = 0; i < 4; ++i) {
            #pragma unroll
            for (int j = 0; j < 4; ++j) {
                __hip_bfloat16 d4[4] = {
                    __float2bfloat16(acc[i][j][0]), __float2bfloat16(acc[i][j][1]),
                    __float2bfloat16(acc[i][j][2]), __float2bfloat16(acc[i][j][3])};
                *(ushort4*)(Db + (co_l0 + j * 16) * 256 + (((m_l0 + i * 16) * 2) ^ key))
                    = *(const ushort4*)d4;
            }
        }
        if (t < 128) red[t] = 0.f;
        __syncthreads();
        const float cf = shifts[b] / fmaxf(sqrtf(normsq[b]), 1e-12f);
        const int kkc = m0 >> 9;
        const int mt0 = m0 >> 5;
        const int ci0 = m0 & 511;
        #pragma unroll
        for (int p = 0; p < 8; ++p) {
            const int idx  = p * 256 + t;
            const int oct  = idx & 3;
            const int mtl  = (idx >> 2) & 3;
            const int co_l = idx >> 4;
            const int co   = co0 + co_l;
            const int swz  = ((co >> 1) & 3) << 3;
            const int m_l  = mtl * 32 + ((oct * 8) ^ swz);
            const int keyr = (co_l & 15) << 4;
            bf16x8 dv = *(const bf16x8*)(Db + co_l * 256 + ((m_l * 2) ^ keyr));
            const int ci = ci0 + m_l;
            bf16x8 wv = *(const bf16x8*)&wgtb[((size_t)co * KK + kkc) * 512 + ci];
            float4 s0 = *(const float4*)&s[b * CIN + ci];
            float4 s1 = *(const float4*)&s[b * CIN + ci + 4];
            float sv[8] = {s0.x, s0.y, s0.z, s0.w, s1.x, s1.y, s1.z, s1.w};
            __hip_bfloat16 vb[8];
            float psum = 0.f;
            #pragma unroll
            for (int e = 0; e < 8; ++e) {
                short sd = dv[e], sw = wv[e];
                float dd = __bfloat162float(*(__hip_bfloat16*)&sd);
                float ww = __bfloat162float(*(__hip_bfloat16*)&sw);
                float v = SCALE_F * (ww + cf * dd) * sv[e];
                vb[e] = __float2bfloat16(v);
                psum += v * v;
            }
            *(bf16x8*)&Wf[(((size_t)b * MT + mt0 + mtl) * COUT + co) * 32 + oct * 8]
                = *(const bf16x8*)vb;
            atomicAdd(&red[co_l], psum);
        }
        __syncthreads();
        if (t < 128) atomicAdd(&demodsq[b * COUT + co0 + t], red[t]);
    }
}

// ---------------------------------------------------------------------------
// K5: grouped conv as MFMA implicit GEMM. 4-buffer pipeline + XCD swizzle
// + incremental B-addressing + setprio.
// ---------------------------------------------------------------------------
__global__ __launch_bounds__(256) void k_conv_mfma(
        const __hip_bfloat16* __restrict__ Wf,     // [b][mt][co][32] swizzled
        const __hip_bfloat16* __restrict__ xh,     // [b][34][34][512]
        const float* __restrict__ demodsq,
        float* __restrict__ out) {
    const int id  = blockIdx.x;
    const int swb = (id & 7) * 64 + (id >> 3);
    const int p0  = (swb & 7) * 128;
    const int co0 = ((swb >> 3) & 3) * 128;
    const int b   = swb >> 5;
    __shared__ __align__(16) char cLDS[4 * 16384];   // 64 KB
    const int t = threadIdx.x;
    const int w = t >> 6, l = t & 63;

    const char* wsrc0 = (const char*)(Wf + (((size_t)b * MT) * COUT + co0) * 32);
    const int lq = l >> 2;
    const int ls = l & 3;
    const int off0 = t * 16;

    const __hip_bfloat16* bsrc0;
    const __hip_bfloat16* bsrc1;

    f32x4 acc[4][4];
    #pragma unroll
    for (int i = 0; i < 4; ++i)
        #pragma unroll
        for (int j = 0; j < 4; ++j) acc[i][j] = (f32x4){0.f, 0.f, 0.f, 0.f};

#define CADDR(mt) {                                                          \
    const int kk_ = (mt) >> 4;                                               \
    const int dy_ = kk_ / 3 - 1, dx_ = kk_ % 3 - 1;                          \
    { int p_l_ = w * 16 + lq; int P_ = p0 + p_l_;                            \
      int yy_ = (P_ >> 5) + dy_ + 1; int xx_ = (P_ & 31) + dx_ + 1;          \
      int sg_ = ls ^ ((p_l_ >> 1) & 3);                                      \
      bsrc0 = xh + (((size_t)b * 34 + yy_) * 34 + xx_) * CIN + sg_ * 8; }    \
    { int p_l_ = 64 + w * 16 + lq; int P_ = p0 + p_l_;                       \
      int yy_ = (P_ >> 5) + dy_ + 1; int xx_ = (P_ & 31) + dx_ + 1;          \
      int sg_ = ls ^ ((p_l_ >> 1) & 3);                                      \
      bsrc1 = xh + (((size_t)b * 34 + yy_) * 34 + xx_) * CIN + sg_ * 8; } }

#define CSTAGE(Ab_, mt) {                                                    \
    if (((mt) & 15) == 0) { CADDR(mt); } else { bsrc0 += 32; bsrc1 += 32; }  \
    const char* wa_ = wsrc0 + (size_t)(mt) * (COUT * 32 * 2);                \
    gload_lds16(wa_ + off0,        (Ab_) + off0);                            \
    gload_lds16(wa_ + off0 + 4096, (Ab_) + off0 + 4096);                     \
    gload_lds16(bsrc0, (Ab_) + 8192 + w * 1024 + l * 16);                    \
    gload_lds16(bsrc1, (Ab_) + 8192 + 4096 + w * 1024 + l * 16); }

#define CCOMPUTE(Ab_) { const char* Bb_ = (Ab_) + 8192;                      \
    bf16x8 fa[4], fb[4];                                                     \
    const int sl = (l >> 4) << 4;                                            \
    const int ar = (w >> 1) * 64 + (l & 15);                                 \
    const int br = (w & 1) * 64 + (l & 15);                                  \
    _Pragma("unroll") for (int i = 0; i < 4; ++i) {                          \
        int r = ar + i * 16;                                                 \
        fa[i] = *(const bf16x8*)((Ab_) + r * 64 + (sl ^ (((r >> 1) & 3) << 4))); \
        int q = br + i * 16;                                                 \
        fb[i] = *(const bf16x8*)(Bb_ + q * 64 + (sl ^ (((q >> 1) & 3) << 4))); } \
    __builtin_amdgcn_s_setprio(1);                                           \
    _Pragma("unroll") for (int i = 0; i < 4; ++i)                            \
        _Pragma("unroll") for (int j = 0; j < 4; ++j)                        \
            acc[i][j] = __builtin_amdgcn_mfma_f32_16x16x32_bf16(fa[i], fb[j], acc[i][j], 0, 0, 0); \
    __builtin_amdgcn_s_setprio(0); }

    CSTAGE(cLDS, 0); CSTAGE(cLDS + 16384, 1); CSTAGE(cLDS + 32768, 2);
    for (int mt = 0; mt < MT - 3; ++mt) {
        CSTAGE(cLDS + ((mt + 3) & 3) * 16384, mt + 3);
        PIPE_WAIT(12);
        CCOMPUTE(cLDS + (mt & 3) * 16384);
        PIPE_END();
    }
    PIPE_WAIT(8); CCOMPUTE(cLDS + ((MT - 3) & 3) * 16384); PIPE_END();
    PIPE_WAIT(4); CCOMPUTE(cLDS + ((MT - 2) & 3) * 16384); PIPE_END();
    PIPE_WAIT(0); CCOMPUTE(cLDS + ((MT - 1) & 3) * 16384);

    const float* dmrow = demodsq + b * COUT;
    #pragma unroll
    for (int i = 0; i < 4; ++i) {
        int co = co0 + (w >> 1) * 64 + i * 16 + (l >> 4) * 4;
        #pragma unroll
        for (int r = 0; r < 4; ++r) {
            float dm = rsqrtf(dmrow[co + r] + 1e-8f);
            #pragma unroll
            for (int j = 0; j < 4; ++j) {
                int p = p0 + (w & 1) * 64 + j * 16 + (l & 15);
                out[((size_t)b * COUT + co + r) * HW + p] = acc[i][j][r] * dm;
            }
        }
    }
}

// ---------------------------------------------------------------------------
extern "C" void kernel_launch(void* const* d_in, const int* in_sizes, int n_in,
                              void* d_out, int out_size, void* d_ws, size_t ws_size,
                              hipStream_t stream) {
    const float* x         = (const float*)d_in[0];
    const float* style     = (const float*)d_in[1];
    const float* mw        = (const float*)d_in[2];
    const float* mb        = (const float*)d_in[3];
    const float* weight    = (const float*)d_in[4];
    const float* u         = (const float*)d_in[5];
    const float* vh        = (const float*)d_in[6];
    const float* dir_delta = (const float*)d_in[7];
    const float* shifts    = (const float*)d_in[8];
    const int*   dirs      = (const int*)d_in[9];
    float* out = (float*)d_out;

    // ---- ws layout (high-water 94,568,448 B — round-4-proven offsets kept)
    char* base = (char*)d_ws;
    float* s       = (float*)(base);                    // 32 KB
    float* demodsq = (float*)(base + 32768);            // 32 KB
    float* normsq  = (float*)(base + 65536);            // 64 B (zero1 spans both)
    char* X = base + 131072;
    __hip_bfloat16* xh = (__hip_bfloat16*)(X);                 // 18.94 MB
    __hip_bfloat16* Wf = (__hip_bfloat16*)(X + 18939904);      // 75.5 MB

    // ---- pre-conv scratch lives in d_out (25.2 MB of 33.55 MB; all dead
    // before k_conv_mfma, which overwrites every byte of d_out each call)
    char* O = (char*)d_out;
    __hip_bfloat16* ubf  = (__hip_bfloat16*)(O);               // 4.72 MB
    __hip_bfloat16* ubfT = (__hip_bfloat16*)(O + 4718592);     // 4.72 MB
    __hip_bfloat16* vt   = (__hip_bfloat16*)(O + 9437184);     // 8.39 MB
    __hip_bfloat16* wgtb = (__hip_bfloat16*)(O + 17825792);    // 4.72 MB
    __hip_bfloat16* vhb  = (__hip_bfloat16*)(O + 22544384);    // 0.52 MB
    float*          Gu   = (float*)(O + 23068672);             // 1 MB
    float*          Gv   = (float*)(O + 24117248);             // 1 MB

    k_prep      <<<dim3(3061),      256, 0, stream>>>(style, mw, mb, s,
                                                      u, ubf, ubfT, vh, vhb,
                                                      dir_delta, dirs, vt,
                                                      weight, wgtb, x, xh,
                                                      demodsq, Gu);
    k_gram2     <<<dim3(8, 8, 11),  256, 0, stream>>>(ubfT, vhb, Gu, Gv);
    k_norm      <<<dim3(BB, 8),     256, 0, stream>>>(Gu, Gv, dir_delta, dirs, normsq);
    k_build_mfma<<<dim3(36, 4, BB), 256, 0, stream>>>(ubf, vt, wgtb, s, normsq, shifts, Wf, demodsq);
    k_conv_mfma <<<dim3(512),       256, 0, stream>>>(Wf, xh, demodsq, out);
}

// Round 15
// 196.951 us; speedup vs baseline: 1.3297x; 1.1729x over previous
//
#include <hip/hip_runtime.h>
#include <hip/hip_bf16.h>

// Problem constants
#define BB   16
#define CIN  512
#define COUT 512
#define KS   3
#define KK   9
#define HH   32
#define WW   32
#define HW   1024
#define SDIM 512
#define RR   512
#define MM   4608               // KK*CIN; m = kk*512 + ci
#define MT   144                // MM/32 k-tiles
#define SCALE_F 0.014731391274719738f  // 1/sqrt(4608)

typedef __attribute__((ext_vector_type(8))) short bf16x8;
typedef __attribute__((ext_vector_type(4))) float f32x4;

__device__ __forceinline__ void gload_lds16(const void* g, void* l) {
    __builtin_amdgcn_global_load_lds(
        (const __attribute__((address_space(1))) unsigned int*)g,
        (__attribute__((address_space(3))) unsigned int*)l,
        16, 0, 0);
}

#define PIPE_WAIT(N) do {                                            \
    asm volatile("s_waitcnt vmcnt(" #N ")" ::: "memory");            \
    __builtin_amdgcn_s_barrier();                                    \
    __builtin_amdgcn_sched_barrier(0); } while (0)
#define PIPE_END() do {                                              \
    __builtin_amdgcn_sched_barrier(0);                               \
    __builtin_amdgcn_s_barrier(); } while (0)

// ---------------------------------------------------------------------------
// K_prep: ONE kernel for every input-only transform (block-uniform sections).
//  [0,32)      : s[b,ci] = style . mw^T + mb
//  [32,608)    : ubf[m][r]=bf16(u), ubfT[r][m]=bf16(u)   (72x8 tiles)
//  [608,736)   : vhb = bf16(vh)
//  [736,1760)  : vt[b][co][r] = bf16(ev_b[r]*vh[r][co])
//  [1760,2272) : wgtb[co][kk][ci] = bf16(weight[co][ci][kk])
//  [2272,2784) : xpose interior (x -> xh NHWC bf16)
//  [2784,2800) : xh halo zero (one block per b)
//  [2800,2805) : zero demodsq+normsq (8208 floats)
//  [2805,3061) : zero Gu+Gv (524288 floats)
// ---------------------------------------------------------------------------
__global__ __launch_bounds__(256) void k_prep(
        const float* __restrict__ style, const float* __restrict__ mw,
        const float* __restrict__ mb, float* __restrict__ s,
        const float* __restrict__ u, __hip_bfloat16* __restrict__ ub,
        __hip_bfloat16* __restrict__ uT,
        const float* __restrict__ vh, __hip_bfloat16* __restrict__ vhb,
        const float* __restrict__ dd, const int* __restrict__ dirs,
        __hip_bfloat16* __restrict__ vt,
        const float* __restrict__ wgt, __hip_bfloat16* __restrict__ wgtb,
        const float* __restrict__ x, __hip_bfloat16* __restrict__ xh,
        float* __restrict__ zero1, float* __restrict__ zero2) {
    const int id = blockIdx.x;
    const int t = threadIdx.x;
    __shared__ __align__(16) char shbuf[18432];

    if (id < 32) {
        int idx = id * 256 + t;
        int b = idx >> 9, ci = idx & 511;
        const float* st = style + (size_t)b * SDIM;
        const float* w  = mw + (size_t)ci * SDIM;
        float acc = 0.f;
        for (int d = 0; d < SDIM; d += 4)
            acc += st[d]*w[d] + st[d+1]*w[d+1] + st[d+2]*w[d+2] + st[d+3]*w[d+3];
        s[idx] = acc + mb[ci];
    } else if (id < 608) {
        __hip_bfloat16 (*tile)[80] = (__hip_bfloat16(*)[80])shbuf;
        const int bx = id - 32;
        const int m0 = (bx % 72) * 64, r0 = (bx / 72) * 64;
        const int ml = t >> 4, rl4 = (t & 15) * 4;
        #pragma unroll
        for (int p = 0; p < 4; ++p) {
            int m_l = ml + p * 16;
            float4 v = *(const float4*)&u[(size_t)(m0 + m_l) * RR + r0 + rl4];
            __hip_bfloat16 b4[4] = {__float2bfloat16(v.x), __float2bfloat16(v.y),
                                    __float2bfloat16(v.z), __float2bfloat16(v.w)};
            *(ushort4*)&ub[(size_t)(m0 + m_l) * RR + r0 + rl4] = *(const ushort4*)b4;
            tile[rl4+0][m_l] = b4[0];
            tile[rl4+1][m_l] = b4[1];
            tile[rl4+2][m_l] = b4[2];
            tile[rl4+3][m_l] = b4[3];
        }
        __syncthreads();
        const int cl = t >> 2, rg = (t & 3) * 16;
        __hip_bfloat16* dst = uT + (size_t)(r0 + cl) * MM + m0 + rg;
        *(bf16x8*)dst       = *(const bf16x8*)&tile[cl][rg];
        *(bf16x8*)(dst + 8) = *(const bf16x8*)&tile[cl][rg + 8];
    } else if (id < 736) {
        size_t i = ((size_t)(id - 608) * 256 + t) * 8;
        float4 a = *(const float4*)(vh + i);
        float4 b = *(const float4*)(vh + i + 4);
        __hip_bfloat16 o[8] = {
            __float2bfloat16(a.x), __float2bfloat16(a.y),
            __float2bfloat16(a.z), __float2bfloat16(a.w),
            __float2bfloat16(b.x), __float2bfloat16(b.y),
            __float2bfloat16(b.z), __float2bfloat16(b.w)};
        *(bf16x8*)(vhb + i) = *(const bf16x8*)o;
    } else if (id < 1760) {
        __hip_bfloat16 (*tile)[80] = (__hip_bfloat16(*)[80])shbuf;
        const int vid = id - 736;
        const int co0 = (vid & 7) * 64, r0 = ((vid >> 3) & 7) * 64, b = vid >> 6;
        const float* ev = dd + (size_t)dirs[b] * RR;
        int tc4 = (t & 15) * 4, tr = t >> 4;
        #pragma unroll
        for (int pass = 0; pass < 4; ++pass) {
            int r = tr + pass * 16;
            float e = ev[r0 + r];
            float4 v = *(const float4*)&vh[(size_t)(r0 + r) * COUT + co0 + tc4];
            tile[tc4+0][r] = __float2bfloat16(v.x * e);
            tile[tc4+1][r] = __float2bfloat16(v.y * e);
            tile[tc4+2][r] = __float2bfloat16(v.z * e);
            tile[tc4+3][r] = __float2bfloat16(v.w * e);
        }
        __syncthreads();
        int cl = t >> 2, rg = (t & 3) * 16;
        __hip_bfloat16* dst = vt + ((size_t)b * COUT + co0 + cl) * RR + r0 + rg;
        *(bf16x8*)dst       = *(const bf16x8*)&tile[cl][rg];
        *(bf16x8*)(dst + 8) = *(const bf16x8*)&tile[cl][rg + 8];
    } else if (id < 2272) {
        float* lw = (float*)shbuf;
        const int co = id - 1760;
        for (int e = t; e < MM; e += 256) lw[e] = wgt[(size_t)co * MM + e];
        __syncthreads();
        for (int e0 = t * 8; e0 < MM; e0 += 2048) {
            int kk = e0 >> 9, ci = e0 & 511;
            __hip_bfloat16 o[8];
            #pragma unroll
            for (int q = 0; q < 8; ++q)
                o[q] = __float2bfloat16(lw[(ci + q) * KK + kk]);
            *(bf16x8*)&wgtb[(size_t)co * MM + e0] = *(const bf16x8*)o;
        }
    } else if (id < 2784) {
        __hip_bfloat16 (*tileT)[72] = (__hip_bfloat16(*)[72])shbuf;
        const int xid = id - 2272;
        const int b = xid >> 5;
        const int y = xid & 31;
        for (int c0 = 0; c0 < CIN; c0 += 64) {
            int ci_l = t >> 2, xq = (t & 3) * 8;
            const float* src = x + (((size_t)(b * CIN + c0 + ci_l)) * HH + y) * WW + xq;
            float4 v0 = *(const float4*)src;
            float4 v1 = *(const float4*)(src + 4);
            __syncthreads();
            tileT[xq+0][ci_l] = __float2bfloat16(v0.x);
            tileT[xq+1][ci_l] = __float2bfloat16(v0.y);
            tileT[xq+2][ci_l] = __float2bfloat16(v0.z);
            tileT[xq+3][ci_l] = __float2bfloat16(v0.w);
            tileT[xq+4][ci_l] = __float2bfloat16(v1.x);
            tileT[xq+5][ci_l] = __float2bfloat16(v1.y);
            tileT[xq+6][ci_l] = __float2bfloat16(v1.z);
            tileT[xq+7][ci_l] = __float2bfloat16(v1.w);
            __syncthreads();
            int x_l = t >> 3, cg = (t & 7) * 8;
            bf16x8 o = *(const bf16x8*)&tileT[x_l][cg];
            *(bf16x8*)&xh[(((size_t)b * 34 + y + 1) * 34 + (x_l + 1)) * CIN + c0 + cg] = o;
        }
    } else if (id < 2800) {
        const int b = id - 2784;
        for (int c = t; c < 132 * 64; c += 256) {
            int cell = c >> 6, part = c & 63;
            int yy, xx;
            if (cell < 34)      { yy = 0;  xx = cell; }
            else if (cell < 68) { yy = 33; xx = cell - 34; }
            else if (cell < 100){ yy = cell - 68 + 1;  xx = 0; }
            else                { yy = cell - 100 + 1; xx = 33; }
            bf16x8 z = {0,0,0,0,0,0,0,0};
            *(bf16x8*)&xh[(((size_t)b * 34 + yy) * 34 + xx) * CIN + part * 8] = z;
        }
    } else if (id < 2805) {
        int idx = (id - 2800) * 2048 + t * 8;
        if (idx < 8208) {
            float4 z = {0.f, 0.f, 0.f, 0.f};
            *(float4*)(zero1 + idx) = z;
            *(float4*)(zero1 + idx + 4) = z;
        }
    } else {
        int idx = (id - 2805) * 2048 + t * 8;
        float4 z = {0.f, 0.f, 0.f, 0.f};
        *(float4*)(zero2 + idx) = z;
        *(float4*)(zero2 + idx + 4) = z;
    }
}

// ---------------------------------------------------------------------------
// K2: merged Gram kernel. z<9: Gu += uT slice; z>=9: Gv += vhb slice.
// 64x64 tile, 4 waves (2x2 of 32x32), BK=32, 4-buffer pipeline, atomic epi.
// ---------------------------------------------------------------------------
__global__ __launch_bounds__(256) void k_gram2(
        const __hip_bfloat16* __restrict__ uT,    // [RR][MM]
        const __hip_bfloat16* __restrict__ vhb,   // [RR][COUT]
        float* __restrict__ Gu, float* __restrict__ Gv) {
    const int r0 = blockIdx.x * 64, r1 = blockIdx.y * 64;
    const int z  = blockIdx.z;
    const bool isGu = (z < 9);
    const __hip_bfloat16* src = isGu ? uT : vhb;
    const int ldb   = (isGu ? MM : COUT) * 2;          // row stride bytes
    const int koff  = isGu ? z * 1024 : (z - 9) * 512; // k offset bytes
    const int NT    = isGu ? 16 : 8;
    float* G = isGu ? Gu : Gv;

    __shared__ __align__(16) char gLDS[4 * 8192];      // 32 KB
    const int t = threadIdx.x;
    const int w = t >> 6, l = t & 63;
    const int row = t >> 2, ls = t & 3;
    const int sg = ls ^ ((row >> 1) & 3);

    const char* sa = (const char*)src + (size_t)(r0 + row) * ldb + koff + sg * 16;
    const char* sb = (const char*)src + (size_t)(r1 + row) * ldb + koff + sg * 16;

    f32x4 acc[2][2];
    #pragma unroll
    for (int i = 0; i < 2; ++i)
        #pragma unroll
        for (int j = 0; j < 2; ++j) acc[i][j] = (f32x4){0.f, 0.f, 0.f, 0.f};

#define GSTAGE(bn, kt) { char* Gb_ = gLDS + (bn) * 8192;                     \
    gload_lds16(sa + (kt) * 64, Gb_ + t * 16);                               \
    gload_lds16(sb + (kt) * 64, Gb_ + 4096 + t * 16); }

#define GCOMP(bn) { const char* Ab_ = gLDS + (bn) * 8192;                    \
    const char* Bb_ = Ab_ + 4096;                                            \
    bf16x8 fa[2], fb[2];                                                     \
    const int sl = (l >> 4) << 4;                                            \
    const int ar = (w >> 1) * 32 + (l & 15);                                 \
    const int br = (w & 1) * 32 + (l & 15);                                  \
    _Pragma("unroll") for (int i = 0; i < 2; ++i) {                          \
        int r = ar + i * 16;                                                 \
        fa[i] = *(const bf16x8*)(Ab_ + r * 64 + (sl ^ (((r >> 1) & 3) << 4))); \
        int q = br + i * 16;                                                 \
        fb[i] = *(const bf16x8*)(Bb_ + q * 64 + (sl ^ (((q >> 1) & 3) << 4))); } \
    __builtin_amdgcn_s_setprio(1);                                           \
    _Pragma("unroll") for (int i = 0; i < 2; ++i)                            \
        _Pragma("unroll") for (int j = 0; j < 2; ++j)                        \
            acc[i][j] = __builtin_amdgcn_mfma_f32_16x16x32_bf16(fa[i], fb[j], acc[i][j], 0, 0, 0); \
    __builtin_amdgcn_s_setprio(0); }

    GSTAGE(0, 0); GSTAGE(1, 1); GSTAGE(2, 2);
    for (int kt = 0; kt < NT - 3; ++kt) {
        GSTAGE((kt + 3) & 3, kt + 3);
        PIPE_WAIT(6);
        GCOMP(kt & 3);
        PIPE_END();
    }
    PIPE_WAIT(4); GCOMP((NT - 3) & 3); PIPE_END();
    PIPE_WAIT(2); GCOMP((NT - 2) & 3); PIPE_END();
    PIPE_WAIT(0); GCOMP((NT - 1) & 3);

    #pragma unroll
    for (int i = 0; i < 2; ++i) {
        const int rA = r0 + (w >> 1) * 32 + i * 16 + (l >> 4) * 4;
        #pragma unroll
        for (int j = 0; j < 2; ++j) {
            const int rB = r1 + (w & 1) * 32 + j * 16 + (l & 15);
            #pragma unroll
            for (int rg = 0; rg < 4; ++rg)
                atomicAdd(&G[(size_t)(rA + rg) * RR + rB], acc[i][j][rg]);
        }
    }
}

// ---------------------------------------------------------------------------
// K3: normsq[b] += slice-sum of ev_r ev_r' Gu[r,r'] Gv[r,r']  (float4 stream)
// ---------------------------------------------------------------------------
__global__ __launch_bounds__(256) void k_norm(const float* __restrict__ Gu,
                                              const float* __restrict__ Gv,
                                              const float* __restrict__ dd,
                                              const int* __restrict__ dirs,
                                              float* __restrict__ normsq) {
    const int b = blockIdx.x, sl = blockIdx.y;
    __shared__ float evs[RR];
    __shared__ float red[256];
    const int t = threadIdx.x;
    const float* ev = dd + (size_t)dirs[b] * RR;
    for (int i = t; i < RR; i += 256) evs[i] = ev[i];
    __syncthreads();
    float acc = 0.f;
    const int base4 = sl * (RR * RR / 32);     // float4 index base
    for (int p4 = base4 + t; p4 < base4 + RR * RR / 32; p4 += 256) {
        float4 gu = ((const float4*)Gu)[p4];
        float4 gv = ((const float4*)Gv)[p4];
        int p = p4 << 2;
        int r = p >> 9, r2 = p & 511;
        acc += evs[r] * (gu.x * gv.x * evs[r2]     + gu.y * gv.y * evs[r2 + 1]
                       + gu.z * gv.z * evs[r2 + 2] + gu.w * gv.w * evs[r2 + 3]);
    }
    red[t] = acc;
    __syncthreads();
    for (int o = 128; o > 0; o >>= 1) {
        if (t < o) red[t] += red[t + o];
        __syncthreads();
    }
    if (t == 0) atomicAdd(&normsq[b], red[0]);
}

// ---------------------------------------------------------------------------
// K4: MFMA delta-GEMM + weight build + demod partials.
// 128x128 tile, 3-buffer ring (48 KB), vmcnt(8), setprio.
// Epilogue: aligned XOR-granule LDS-bounce + shfl-reduced demod atomics.
// ---------------------------------------------------------------------------
__global__ __launch_bounds__(256) void k_build_mfma(
        const __hip_bfloat16* __restrict__ ubf,   // [MM][RR]
        const __hip_bfloat16* __restrict__ vt,    // [B][COUT][RR]
        const __hip_bfloat16* __restrict__ wgtb,  // [COUT][9][512] bf16
        const float* __restrict__ s,              // [B][CIN]
        const float* __restrict__ normsq,
        const float* __restrict__ shifts,
        __hip_bfloat16* __restrict__ Wf,          // [B][MT][COUT][32] swizzled
        float* __restrict__ demodsq) {
    const int m0  = blockIdx.x * 128;
    const int co0 = blockIdx.y * 128;
    const int b   = blockIdx.z;
    __shared__ __align__(16) char bLDS[3 * 16384];   // 48 KB (ring; reused by epilogue)
    const int t = threadIdx.x;
    const int w = t >> 6, l = t & 63;
    const int row = t >> 2, ls = t & 3;
    const int sg  = ls ^ ((row >> 1) & 3);

    const char* ua  = (const char*)(ubf + (size_t)(m0 + row) * RR) + sg * 16;
    const char* ua2 = ua + (size_t)64 * RR * 2;
    const char* va  = (const char*)(vt + ((size_t)b * COUT + co0 + row) * RR) + sg * 16;
    const char* va2 = va + (size_t)64 * RR * 2;
    const int dst0 = t * 16;

    f32x4 acc[4][4];
    #pragma unroll
    for (int i = 0; i < 4; ++i)
        #pragma unroll
        for (int j = 0; j < 4; ++j) acc[i][j] = (f32x4){0.f, 0.f, 0.f, 0.f};

#define BSTAGE(Ab_, kt) { const int rb = (kt) * 64;                          \
    gload_lds16(ua  + rb, (Ab_) + dst0);                                     \
    gload_lds16(ua2 + rb, (Ab_) + dst0 + 4096);                              \
    gload_lds16(va  + rb, (Ab_) + 8192 + dst0);                              \
    gload_lds16(va2 + rb, (Ab_) + 8192 + dst0 + 4096); }

#define BCOMPUTE(Ab_) { const char* Bb_ = (Ab_) + 8192;                      \
    bf16x8 fa[4], fb[4];                                                     \
    const int sl = (l >> 4) << 4;                                            \
    const int ar = (w >> 1) * 64 + (l & 15);                                 \
    const int br = (w & 1) * 64 + (l & 15);                                  \
    _Pragma("unroll") for (int i = 0; i < 4; ++i) {                          \
        int r = ar + i * 16;                                                 \
        fa[i] = *(const bf16x8*)((Ab_) + r * 64 + (sl ^ (((r >> 1) & 3) << 4))); \
        int q = br + i * 16;                                                 \
        fb[i] = *(const bf16x8*)(Bb_ + q * 64 + (sl ^ (((q >> 1) & 3) << 4))); } \
    __builtin_amdgcn_s_setprio(1);                                           \
    _Pragma("unroll") for (int i = 0; i < 4; ++i)                            \
        _Pragma("unroll") for (int j = 0; j < 4; ++j)                        \
            acc[i][j] = __builtin_amdgcn_mfma_f32_16x16x32_bf16(fa[i], fb[j], acc[i][j], 0, 0, 0); \
    __builtin_amdgcn_s_setprio(0); }

    char* cbuf = bLDS;
    char* nbuf = bLDS + 16384;
    char* sbuf = bLDS + 32768;
    BSTAGE(cbuf, 0); BSTAGE(nbuf, 1);
    for (int kt = 0; kt < 14; ++kt) {
        BSTAGE(sbuf, kt + 2);
        PIPE_WAIT(8);
        BCOMPUTE(cbuf);
        PIPE_END();
        char* tmp = cbuf; cbuf = nbuf; nbuf = sbuf; sbuf = tmp;
    }
    PIPE_WAIT(4); BCOMPUTE(cbuf); PIPE_END();   // kt=14
    PIPE_WAIT(0); BCOMPUTE(nbuf);               // kt=15

    // ---- epilogue: LDS-bounce, stride 256 B + 16B-granule XOR swizzle
    // byte(co, m) = co*256 + ((2m) ^ ((co&15)<<4))  — aligned, conflict-free
    __syncthreads();
    {
        char* Db = bLDS;                              // 128 x 256 B = 32 KB
        float* red = (float*)(bLDS + 32768);          // 128 floats
        const int co_l0 = (w & 1) * 64 + (l & 15);
        const int m_l0  = (w >> 1) * 64 + (l >> 4) * 4;
        const int key   = (l & 15) << 4;              // == (co&15)<<4 for all j
        #pragma unroll
        for (int i = 0; i < 4; ++i) {
            #pragma unroll
            for (int j = 0; j < 4; ++j) {
                __hip_bfloat16 d4[4] = {
                    __float2bfloat16(acc[i][j][0]), __float2bfloat16(acc[i][j][1]),
                    __float2bfloat16(acc[i][j][2]), __float2bfloat16(acc[i][j][3])};
                *(ushort4*)(Db + (co_l0 + j * 16) * 256 + (((m_l0 + i * 16) * 2) ^ key))
                    = *(const ushort4*)d4;
            }
        }
        if (t < 128) red[t] = 0.f;
        __syncthreads();
        const float cf = shifts[b] / fmaxf(sqrtf(normsq[b]), 1e-12f);
        const int kkc = m0 >> 9;
        const int mt0 = m0 >> 5;
        const int ci0 = m0 & 511;
        #pragma unroll
        for (int p = 0; p < 8; ++p) {
            const int idx  = p * 256 + t;
            const int oct  = idx & 3;
            const int mtl  = (idx >> 2) & 3;
            const int co_l = idx >> 4;
            const int co   = co0 + co_l;
            const int swz  = ((co >> 1) & 3) << 3;
            const int m_l  = mtl * 32 + ((oct * 8) ^ swz);
            const int keyr = (co_l & 15) << 4;
            bf16x8 dv = *(const bf16x8*)(Db + co_l * 256 + ((m_l * 2) ^ keyr));
            const int ci = ci0 + m_l;
            bf16x8 wv = *(const bf16x8*)&wgtb[((size_t)co * KK + kkc) * 512 + ci];
            float4 s0 = *(const float4*)&s[b * CIN + ci];
            float4 s1 = *(const float4*)&s[b * CIN + ci + 4];
            float sv[8] = {s0.x, s0.y, s0.z, s0.w, s1.x, s1.y, s1.z, s1.w};
            __hip_bfloat16 vb[8];
            float psum = 0.f;
            #pragma unroll
            for (int e = 0; e < 8; ++e) {
                short sd = dv[e], sw = wv[e];
                float dd = __bfloat162float(*(__hip_bfloat16*)&sd);
                float ww = __bfloat162float(*(__hip_bfloat16*)&sw);
                float v = SCALE_F * (ww + cf * dd) * sv[e];
                vb[e] = __float2bfloat16(v);
                psum += v * v;
            }
            *(bf16x8*)&Wf[(((size_t)b * MT + mt0 + mtl) * COUT + co) * 32 + oct * 8]
                = *(const bf16x8*)vb;
            // 16 consecutive lanes share co_l: shfl-reduce, 1 atomic per group
            #pragma unroll
            for (int o = 1; o < 16; o <<= 1) psum += __shfl_xor(psum, o);
            if ((l & 15) == 0) atomicAdd(&red[co_l], psum);
        }
        __syncthreads();
        if (t < 128) atomicAdd(&demodsq[b * COUT + co0 + t], red[t]);
    }
}

// ---------------------------------------------------------------------------
// K5: grouped conv as MFMA implicit GEMM. 4-buffer pipeline + XCD swizzle
// + incremental B-addressing + setprio.
// ---------------------------------------------------------------------------
__global__ __launch_bounds__(256) void k_conv_mfma(
        const __hip_bfloat16* __restrict__ Wf,     // [b][mt][co][32] swizzled
        const __hip_bfloat16* __restrict__ xh,     // [b][34][34][512]
        const float* __restrict__ demodsq,
        float* __restrict__ out) {
    const int id  = blockIdx.x;
    const int swb = (id & 7) * 64 + (id >> 3);
    const int p0  = (swb & 7) * 128;
    const int co0 = ((swb >> 3) & 3) * 128;
    const int b   = swb >> 5;
    __shared__ __align__(16) char cLDS[4 * 16384];   // 64 KB
    const int t = threadIdx.x;
    const int w = t >> 6, l = t & 63;

    const char* wsrc0 = (const char*)(Wf + (((size_t)b * MT) * COUT + co0) * 32);
    const int lq = l >> 2;
    const int ls = l & 3;
    const int off0 = t * 16;

    const __hip_bfloat16* bsrc0;
    const __hip_bfloat16* bsrc1;

    f32x4 acc[4][4];
    #pragma unroll
    for (int i = 0; i < 4; ++i)
        #pragma unroll
        for (int j = 0; j < 4; ++j) acc[i][j] = (f32x4){0.f, 0.f, 0.f, 0.f};

#define CADDR(mt) {                                                          \
    const int kk_ = (mt) >> 4;                                               \
    const int dy_ = kk_ / 3 - 1, dx_ = kk_ % 3 - 1;                          \
    { int p_l_ = w * 16 + lq; int P_ = p0 + p_l_;                            \
      int yy_ = (P_ >> 5) + dy_ + 1; int xx_ = (P_ & 31) + dx_ + 1;          \
      int sg_ = ls ^ ((p_l_ >> 1) & 3);                                      \
      bsrc0 = xh + (((size_t)b * 34 + yy_) * 34 + xx_) * CIN + sg_ * 8; }    \
    { int p_l_ = 64 + w * 16 + lq; int P_ = p0 + p_l_;                       \
      int yy_ = (P_ >> 5) + dy_ + 1; int xx_ = (P_ & 31) + dx_ + 1;          \
      int sg_ = ls ^ ((p_l_ >> 1) & 3);                                      \
      bsrc1 = xh + (((size_t)b * 34 + yy_) * 34 + xx_) * CIN + sg_ * 8; } }

#define CSTAGE(Ab_, mt) {                                                    \
    if (((mt) & 15) == 0) { CADDR(mt); } else { bsrc0 += 32; bsrc1 += 32; }  \
    const char* wa_ = wsrc0 + (size_t)(mt) * (COUT * 32 * 2);                \
    gload_lds16(wa_ + off0,        (Ab_) + off0);                            \
    gload_lds16(wa_ + off0 + 4096, (Ab_) + off0 + 4096);                     \
    gload_lds16(bsrc0, (Ab_) + 8192 + w * 1024 + l * 16);                    \
    gload_lds16(bsrc1, (Ab_) + 8192 + 4096 + w * 1024 + l * 16); }

#define CCOMPUTE(Ab_) { const char* Bb_ = (Ab_) + 8192;                      \
    bf16x8 fa[4], fb[4];                                                     \
    const int sl = (l >> 4) << 4;                                            \
    const int ar = (w >> 1) * 64 + (l & 15);                                 \
    const int br = (w & 1) * 64 + (l & 15);                                  \
    _Pragma("unroll") for (int i = 0; i < 4; ++i) {                          \
        int r = ar + i * 16;                                                 \
        fa[i] = *(const bf16x8*)((Ab_) + r * 64 + (sl ^ (((r >> 1) & 3) << 4))); \
        int q = br + i * 16;                                                 \
        fb[i] = *(const bf16x8*)(Bb_ + q * 64 + (sl ^ (((q >> 1) & 3) << 4))); } \
    __builtin_amdgcn_s_setprio(1);                                           \
    _Pragma("unroll") for (int i = 0; i < 4; ++i)                            \
        _Pragma("unroll") for (int j = 0; j < 4; ++j)                        \
            acc[i][j] = __builtin_amdgcn_mfma_f32_16x16x32_bf16(fa[i], fb[j], acc[i][j], 0, 0, 0); \
    __builtin_amdgcn_s_setprio(0); }

    CSTAGE(cLDS, 0); CSTAGE(cLDS + 16384, 1); CSTAGE(cLDS + 32768, 2);
    for (int mt = 0; mt < MT - 3; ++mt) {
        CSTAGE(cLDS + ((mt + 3) & 3) * 16384, mt + 3);
        PIPE_WAIT(12);
        CCOMPUTE(cLDS + (mt & 3) * 16384);
        PIPE_END();
    }
    PIPE_WAIT(8); CCOMPUTE(cLDS + ((MT - 3) & 3) * 16384); PIPE_END();
    PIPE_WAIT(4); CCOMPUTE(cLDS + ((MT - 2) & 3) * 16384); PIPE_END();
    PIPE_WAIT(0); CCOMPUTE(cLDS + ((MT - 1) & 3) * 16384);

    const float* dmrow = demodsq + b * COUT;
    #pragma unroll
    for (int i = 0; i < 4; ++i) {
        int co = co0 + (w >> 1) * 64 + i * 16 + (l >> 4) * 4;
        #pragma unroll
        for (int r = 0; r < 4; ++r) {
            float dm = rsqrtf(dmrow[co + r] + 1e-8f);
            #pragma unroll
            for (int j = 0; j < 4; ++j) {
                int p = p0 + (w & 1) * 64 + j * 16 + (l & 15);
                out[((size_t)b * COUT + co + r) * HW + p] = acc[i][j][r] * dm;
            }
        }
    }
}

// ---------------------------------------------------------------------------
extern "C" void kernel_launch(void* const* d_in, const int* in_sizes, int n_in,
                              void* d_out, int out_size, void* d_ws, size_t ws_size,
                              hipStream_t stream) {
    const float* x         = (const float*)d_in[0];
    const float* style     = (const float*)d_in[1];
    const float* mw        = (const float*)d_in[2];
    const float* mb        = (const float*)d_in[3];
    const float* weight    = (const float*)d_in[4];
    const float* u         = (const float*)d_in[5];
    const float* vh        = (const float*)d_in[6];
    const float* dir_delta = (const float*)d_in[7];
    const float* shifts    = (const float*)d_in[8];
    const int*   dirs      = (const int*)d_in[9];
    float* out = (float*)d_out;

    // ---- ws layout (high-water 94,568,448 B — round-4-proven offsets kept)
    char* base = (char*)d_ws;
    float* s       = (float*)(base);                    // 32 KB
    float* demodsq = (float*)(base + 32768);            // 32 KB
    float* normsq  = (float*)(base + 65536);            // 64 B (zero1 spans both)
    char* X = base + 131072;
    __hip_bfloat16* xh = (__hip_bfloat16*)(X);                 // 18.94 MB
    __hip_bfloat16* Wf = (__hip_bfloat16*)(X + 18939904);      // 75.5 MB

    // ---- pre-conv scratch lives in d_out (25.2 MB of 33.55 MB; all dead
    // before k_conv_mfma, which overwrites every byte of d_out each call)
    char* O = (char*)d_out;
    __hip_bfloat16* ubf  = (__hip_bfloat16*)(O);               // 4.72 MB
    __hip_bfloat16* ubfT = (__hip_bfloat16*)(O + 4718592);     // 4.72 MB
    __hip_bfloat16* vt   = (__hip_bfloat16*)(O + 9437184);     // 8.39 MB
    __hip_bfloat16* wgtb = (__hip_bfloat16*)(O + 17825792);    // 4.72 MB
    __hip_bfloat16* vhb  = (__hip_bfloat16*)(O + 22544384);    // 0.52 MB
    float*          Gu   = (float*)(O + 23068672);             // 1 MB
    float*          Gv   = (float*)(O + 24117248);             // 1 MB

    k_prep      <<<dim3(3061),      256, 0, stream>>>(style, mw, mb, s,
                                                      u, ubf, ubfT, vh, vhb,
                                                      dir_delta, dirs, vt,
                                                      weight, wgtb, x, xh,
                                                      demodsq, Gu);
    k_gram2     <<<dim3(8, 8, 11),  256, 0, stream>>>(ubfT, vhb, Gu, Gv);
    k_norm      <<<dim3(BB, 8),     256, 0, stream>>>(Gu, Gv, dir_delta, dirs, normsq);
    k_build_mfma<<<dim3(36, 4, BB), 256, 0, stream>>>(ubf, vt, wgtb, s, normsq, shifts, Wf, demodsq);
    k_conv_mfma <<<dim3(512),       256, 0, stream>>>(Wf, xh, demodsq, out);
}